// Round 13
// baseline (58.523 us; speedup 1.0000x reference)
//
#include <hip/hip_runtime.h>

// ABELSpline: B=1024, D=128, DENSITY=259, ODIM=64, IDIM=512
// out[b,o] = direct[b,o] + sum_n c_n*(exp(z[b,8o+n]) - exp(z[b,8o+4+n])), c_n=(n+1)^-2
// direct[b,o] = sum_{d,k} w[b,d,k] * dtab[d*259 + p[b,d] + k, o]
// z[b,j]      = sum_{d,k} w[b,d,k] * itab[d*259 + p[b,d] + k, j]
// p = floor(256*x); p+3 <= 258 so the reference's mod never wraps.
//
// Round 12: SLICE-LOCAL REPACK. R11 (wide 16B/lane gathers) cut main to ~33us,
// total 55 (repack ~20). The old repack was row-parallel: every block wrote to
// all 8 slices, scattering each slice's fp16 stripe across all XCDs' L2s ->
// main re-fetched ~50MB from L3. Now repack block (slice=bid&7, 128-row chunk)
// reads only its slice's source cols (256B segments) and writes the packed
// stripe locally -> slice s's 4.7MB sits DIRTY in XCD s's L2 when main (same
// bid&7 map) reads it. Main unchanged (single-variable change).

constexpr int BATCH = 1024;
constexpr int DIN = 128;
constexpr int DENSITY = 259;
constexpr int ODIM = 64;
constexpr int IDIM = 512;
constexpr int SLICES = 8;           // = #XCDs; 8 outputs / 64 indirect cols each
constexpr int RPB = 8;              // batch rows per block
constexpr int TPB = 512;            // 8 waves; wave wv: rows 2*(wv&3),+1; dims (wv>>2)*64..+63
constexpr int ROWS = DIN * DENSITY; // 33152 table rows = 259 * 128
constexpr size_t WSI_ELEMS = (size_t)SLICES * ROWS * 64;  // fp16 indirect repack
constexpr size_t WSD_ELEMS = (size_t)SLICES * ROWS * 8;   // fp16 direct repack
constexpr size_t WS_NEEDED = (WSI_ELEMS + WSD_ELEMS) * 2; // 38,191,104 B

typedef _Float16 h8 __attribute__((ext_vector_type(8)));
typedef _Float16 h4 __attribute__((ext_vector_type(4)));

__device__ __forceinline__ void fma4(float4& a, float s, const float4 v) {
    a.x = fmaf(s, v.x, a.x);
    a.y = fmaf(s, v.y, a.y);
    a.z = fmaf(s, v.z, a.z);
    a.w = fmaf(s, v.w, a.w);
}

__device__ __forceinline__ void fma8h(float4& lo, float4& hi, float s, const h8 v) {
    lo.x = fmaf(s, (float)v[0], lo.x);   // -> v_fma_mix_f32
    lo.y = fmaf(s, (float)v[1], lo.y);
    lo.z = fmaf(s, (float)v[2], lo.z);
    lo.w = fmaf(s, (float)v[3], lo.w);
    hi.x = fmaf(s, (float)v[4], hi.x);
    hi.y = fmaf(s, (float)v[5], hi.y);
    hi.z = fmaf(s, (float)v[6], hi.z);
    hi.w = fmaf(s, (float)v[7], hi.w);
}

__device__ __forceinline__ void add4(float4& a, const float4 t) {
    a.x += t.x; a.y += t.y; a.z += t.z; a.w += t.w;
}

__device__ __forceinline__ float4 shfl_xor4(float4 v, int m) {
    return make_float4(__shfl_xor(v.x, m), __shfl_xor(v.y, m),
                       __shfl_xor(v.z, m), __shfl_xor(v.w, m));
}

// ---- slice-local repack: block (slice = bid&7, chunk = bid>>3) handles 128
// rows of ITS slice only. Reads: 256B segments (indirect) / 32B (direct) of
// the source rows. Writes: packed stripe rows, 1KB-contiguous per wave,
// landing dirty in the local XCD's L2 for the main kernel to hit.
__global__ __launch_bounds__(256) void repack_kernel(
    const float* __restrict__ dtab,
    const float* __restrict__ itab,
    _Float16* __restrict__ wsI,
    _Float16* __restrict__ wsD)
{
    const int bid   = blockIdx.x;
    const int slice = bid & (SLICES - 1);
    const int chunk = bid >> 3;            // 0..258
    const int t     = threadIdx.x;
    const int row0  = chunk * 128;

    // indirect: 4 passes x (32 rows x 8 col-octs); 32B read, 16B write per thread
    {
        const int c8 = t & 7;
        const int rr = t >> 3;             // 0..31
        #pragma unroll
        for (int p = 0; p < 4; ++p) {
            const int row = row0 + p * 32 + rr;
            const float4* src = (const float4*)(itab + (size_t)row * IDIM + slice * 64 + c8 * 8);
            const float4 v0 = src[0];
            const float4 v1 = src[1];
            h8 o = { (_Float16)v0.x, (_Float16)v0.y, (_Float16)v0.z, (_Float16)v0.w,
                     (_Float16)v1.x, (_Float16)v1.y, (_Float16)v1.z, (_Float16)v1.w };
            *((h8*)wsI + ((size_t)slice * ROWS + row) * 8 + c8) = o;
        }
    }
    // direct: 1 pass: rr = t>>1 (0..127), j = t&1; 16B read, 8B write per thread
    {
        const int j  = t & 1;
        const int rr = t >> 1;             // 0..127
        const int row = row0 + rr;
        const float4 v = *(const float4*)(dtab + (size_t)row * ODIM + slice * 8 + j * 4);
        h4 o = { (_Float16)v.x, (_Float16)v.y, (_Float16)v.z, (_Float16)v.w };
        *((h4*)wsD + ((size_t)slice * ROWS + row) * 2 + j) = o;
    }
}

// ---- main kernel, fp16 slice-major tables, wide 16B/lane gathers (R11)
__global__ __launch_bounds__(TPB) void abel_f16_kernel(
    const float* __restrict__ x,
    const _Float16* __restrict__ wsI,
    const _Float16* __restrict__ wsD,
    float* __restrict__ out)
{
    __shared__ float4 s_w[RPB][DIN];        // spline weights per (row, dim)
    __shared__ int    s_base[RPB][DIN];     // d*259 + floor(256*x)
    __shared__ float  s_zp[2][RPB][64];     // per-half indirect partials
    __shared__ float  s_dp[2][RPB][8];      // per-half direct partials (8 cols)

    const int bid   = blockIdx.x;
    const int slice = bid & (SLICES - 1);   // round-robin -> XCD-pinned stripe
    const int chunk = bid >> 3;             // 0..127
    const int tid   = threadIdx.x;
    const int wv    = tid >> 6;             // 0..7
    const int half  = wv >> 2;              // dim half: 0 or 1
    const int wp    = wv & 3;               // row-pair index
    const int lane  = tid & 63;
    const int rowbase = chunk * RPB;
    const int r0 = 2 * wp, r1 = 2 * wp + 1;
    const int dBeg = half * 64;

    // ---- phase 1: weights + base row index for all (r,d) pairs (2 iters)
    for (int i = tid; i < RPB * DIN; i += TPB) {
        const int r = i >> 7;       // 0..7
        const int d = i & 127;
        float xv = x[(rowbase + r) * DIN + d];
        float t  = xv * 256.0f;     // scale = DENSITY-3 = 256
        float fl = floorf(t);
        float f  = t - fl;
        float f2 = f * f;
        float f3 = f2 * f;
        float om = 1.0f - f;
        float w0 = om * om * om * (1.0f / 6.0f);
        float w1 = (3.0f * f3 - 6.0f * f2 + 4.0f) * (1.0f / 6.0f);
        float w2 = (-3.0f * f3 + 3.0f * f2 + 3.0f * f + 1.0f) * (1.0f / 6.0f);
        float w3 = f3 * (1.0f / 6.0f);
        s_w[r][d]    = make_float4(w0, w1, w2, w3);
        s_base[r][d] = d * DENSITY + (int)fl;
    }
    __syncthreads();

    // ---- phase 2a: indirect stripe, 16B/lane gathers, 2 dims per wave-load.
    // lane = hI (bit5: dim parity) | qI (bits 3-4: knot) | c8 (bits 0-2: col-oct)
    // byte voffset = (base<<7) + (qI<<7) + (c8<<4); one load covers dims d,d+1.
    const int c8 = lane & 7;
    const int qI = (lane >> 3) & 3;
    const int hI = lane >> 5;
    const char* __restrict__ itRaw = (const char*)wsI + (size_t)slice * ROWS * 128;
    const int laneOffI = (qI << 7) + (c8 << 4);

    float4 a0lo = make_float4(0.f, 0.f, 0.f, 0.f);
    float4 a0hi = make_float4(0.f, 0.f, 0.f, 0.f);
    float4 a1lo = make_float4(0.f, 0.f, 0.f, 0.f);
    float4 a1hi = make_float4(0.f, 0.f, 0.f, 0.f);

    #pragma unroll 4
    for (int d = dBeg; d < dBeg + 64; d += 2) {
        const int   dA = d + hI;
        const int   b0 = s_base[r0][dA];
        const int   b1 = s_base[r1][dA];
        const float w0 = ((const float*)&s_w[r0][dA])[qI];
        const float w1 = ((const float*)&s_w[r1][dA])[qI];
        const h8 u0 = *(const h8*)(itRaw + ((b0 << 7) + laneOffI));
        const h8 u1 = *(const h8*)(itRaw + ((b1 << 7) + laneOffI));
        fma8h(a0lo, a0hi, w0, u0);
        fma8h(a1lo, a1hi, w1, u1);
    }
    // reduce over qI (bits 3-4) and hI (bit 5)
    add4(a0lo, shfl_xor4(a0lo, 8));  add4(a0hi, shfl_xor4(a0hi, 8));
    add4(a0lo, shfl_xor4(a0lo, 16)); add4(a0hi, shfl_xor4(a0hi, 16));
    add4(a0lo, shfl_xor4(a0lo, 32)); add4(a0hi, shfl_xor4(a0hi, 32));
    add4(a1lo, shfl_xor4(a1lo, 8));  add4(a1hi, shfl_xor4(a1hi, 8));
    add4(a1lo, shfl_xor4(a1lo, 16)); add4(a1hi, shfl_xor4(a1hi, 16));
    add4(a1lo, shfl_xor4(a1lo, 32)); add4(a1hi, shfl_xor4(a1hi, 32));
    if (lane < 8) {   // lane == c8: owns cols c8*8..c8*8+7
        reinterpret_cast<float4*>(s_zp[half][r0])[c8 * 2]     = a0lo;
        reinterpret_cast<float4*>(s_zp[half][r0])[c8 * 2 + 1] = a0hi;
        reinterpret_cast<float4*>(s_zp[half][r1])[c8 * 2]     = a1lo;
        reinterpret_cast<float4*>(s_zp[half][r1])[c8 * 2 + 1] = a1hi;
    }

    // ---- phase 2b: direct stripe (8 cols), 16B/lane = 8 cols of one knot-row;
    // lane = dd16 (bits 2-5: 16 dims per load) | qD (bits 0-1: knot).
    // byte voffset = (base<<4) + (qD<<4).
    const int qD   = lane & 3;
    const int dd16 = lane >> 2;
    const char* __restrict__ dtRaw = (const char*)wsD + (size_t)slice * ROWS * 16;
    const int laneOffD = qD << 4;

    float4 aD0lo = make_float4(0.f, 0.f, 0.f, 0.f);
    float4 aD0hi = make_float4(0.f, 0.f, 0.f, 0.f);
    float4 aD1lo = make_float4(0.f, 0.f, 0.f, 0.f);
    float4 aD1hi = make_float4(0.f, 0.f, 0.f, 0.f);

    #pragma unroll
    for (int d0 = dBeg; d0 < dBeg + 64; d0 += 16) {
        const int   dA  = d0 + dd16;
        const int   bD0 = s_base[r0][dA];
        const int   bD1 = s_base[r1][dA];
        const float wD0 = ((const float*)&s_w[r0][dA])[qD];
        const float wD1 = ((const float*)&s_w[r1][dA])[qD];
        const h8 g0 = *(const h8*)(dtRaw + ((bD0 << 4) + laneOffD));
        const h8 g1 = *(const h8*)(dtRaw + ((bD1 << 4) + laneOffD));
        fma8h(aD0lo, aD0hi, wD0, g0);
        fma8h(aD1lo, aD1hi, wD1, g1);
    }
    // full-wave reduce (all lanes hold partials of the same 8 direct cols)
    #pragma unroll
    for (int m = 1; m <= 32; m <<= 1) {
        add4(aD0lo, shfl_xor4(aD0lo, m)); add4(aD0hi, shfl_xor4(aD0hi, m));
        add4(aD1lo, shfl_xor4(aD1lo, m)); add4(aD1hi, shfl_xor4(aD1hi, m));
    }
    if (lane == 0) {
        reinterpret_cast<float4*>(s_dp[half][r0])[0] = aD0lo;
        reinterpret_cast<float4*>(s_dp[half][r0])[1] = aD0hi;
        reinterpret_cast<float4*>(s_dp[half][r1])[0] = aD1lo;
        reinterpret_cast<float4*>(s_dp[half][r1])[1] = aD1hi;
    }
    __syncthreads();

    // ---- phase 3: epilogue, 64 threads = 8 rows x 8 outputs; sum the two halves
    if (tid < RPB * 8) {
        const int r  = tid >> 3;
        const int oo = tid & 7;
        float dir = s_dp[0][r][oo] + s_dp[1][r][oo];
        const float* z0 = s_zp[0][r] + oo * 8;
        const float* z1 = s_zp[1][r] + oo * 8;
        float pos = __expf(z0[0] + z1[0]) + 0.25f * __expf(z0[1] + z1[1])
                  + (1.0f / 9.0f) * __expf(z0[2] + z1[2]) + 0.0625f * __expf(z0[3] + z1[3]);
        float neg = __expf(z0[4] + z1[4]) + 0.25f * __expf(z0[5] + z1[5])
                  + (1.0f / 9.0f) * __expf(z0[6] + z1[6]) + 0.0625f * __expf(z0[7] + z1[7]);
        out[(rowbase + r) * ODIM + slice * 8 + oo] = dir + pos - neg;
    }
}

// ---- fp32 fallback (round-7 kernel) for ws_size < WS_NEEDED
__global__ __launch_bounds__(256) void abel_fp32_kernel(
    const float* __restrict__ x,
    const float* __restrict__ dtab,
    const float* __restrict__ itab,
    float* __restrict__ out)
{
    __shared__ float4 s_w[RPB][DIN];
    __shared__ int    s_base[RPB][DIN];
    __shared__ float  s_z[RPB][64];
    __shared__ float4 s_dir4[RPB][2];

    const int bid   = blockIdx.x;
    const int slice = bid & (SLICES - 1);
    const int chunk = bid >> 3;
    const int tid   = threadIdx.x;
    const int wv    = tid >> 6;
    const int lane  = tid & 63;
    const int rowbase = chunk * RPB;

    for (int i = tid; i < RPB * DIN; i += 256) {
        const int r = i >> 7;
        const int d = i & 127;
        float xv = x[(rowbase + r) * DIN + d];
        float t  = xv * 256.0f;
        float fl = floorf(t);
        float f  = t - fl;
        float f2 = f * f;
        float f3 = f2 * f;
        float om = 1.0f - f;
        float w0 = om * om * om * (1.0f / 6.0f);
        float w1 = (3.0f * f3 - 6.0f * f2 + 4.0f) * (1.0f / 6.0f);
        float w2 = (-3.0f * f3 + 3.0f * f2 + 3.0f * f + 1.0f) * (1.0f / 6.0f);
        float w3 = f3 * (1.0f / 6.0f);
        s_w[r][d]    = make_float4(w0, w1, w2, w3);
        s_base[r][d] = d * DENSITY + (int)fl;
    }
    __syncthreads();

    const int q  = lane >> 4;
    const int c4 = lane & 15;
    const float* __restrict__ itL = itab + (size_t)q * IDIM + slice * 64 + c4 * 4;
    const int r0 = 2 * wv, r1 = 2 * wv + 1;

    float4 a0 = make_float4(0.f, 0.f, 0.f, 0.f);
    float4 a1 = make_float4(0.f, 0.f, 0.f, 0.f);
    #pragma unroll 2
    for (int d = 0; d < DIN; ++d) {
        const int   b0 = s_base[r0][d];
        const int   b1 = s_base[r1][d];
        const float w0 = ((const float*)&s_w[r0][d])[q];
        const float w1 = ((const float*)&s_w[r1][d])[q];
        float4 v0 = *(const float4*)(itL + (size_t)b0 * IDIM);
        float4 v1 = *(const float4*)(itL + (size_t)b1 * IDIM);
        fma4(a0, w0, v0);
        fma4(a1, w1, v1);
    }
    add4(a0, shfl_xor4(a0, 16));
    add4(a0, shfl_xor4(a0, 32));
    add4(a1, shfl_xor4(a1, 16));
    add4(a1, shfl_xor4(a1, 32));
    if (q == 0) {
        reinterpret_cast<float4*>(s_z[r0])[c4] = a0;
        reinterpret_cast<float4*>(s_z[r1])[c4] = a1;
    }

    const int dd = lane >> 3;
    const int qD = (lane >> 1) & 3;
    const int jD = lane & 1;
    const float* __restrict__ dtL = dtab + (size_t)qD * ODIM + slice * 8 + jD * 4;

    float4 aD0 = make_float4(0.f, 0.f, 0.f, 0.f);
    float4 aD1 = make_float4(0.f, 0.f, 0.f, 0.f);
    #pragma unroll 2
    for (int d0 = 0; d0 < DIN; d0 += 8) {
        const int   dA  = d0 + dd;
        const int   bD0 = s_base[r0][dA];
        const int   bD1 = s_base[r1][dA];
        const float wD0 = ((const float*)&s_w[r0][dA])[qD];
        const float wD1 = ((const float*)&s_w[r1][dA])[qD];
        float4 u0 = *(const float4*)(dtL + (size_t)bD0 * ODIM);
        float4 u1 = *(const float4*)(dtL + (size_t)bD1 * ODIM);
        fma4(aD0, wD0, u0);
        fma4(aD1, wD1, u1);
    }
    add4(aD0, shfl_xor4(aD0, 2));
    add4(aD0, shfl_xor4(aD0, 4));
    add4(aD0, shfl_xor4(aD0, 8));
    add4(aD0, shfl_xor4(aD0, 16));
    add4(aD0, shfl_xor4(aD0, 32));
    add4(aD1, shfl_xor4(aD1, 2));
    add4(aD1, shfl_xor4(aD1, 4));
    add4(aD1, shfl_xor4(aD1, 8));
    add4(aD1, shfl_xor4(aD1, 16));
    add4(aD1, shfl_xor4(aD1, 32));
    if (lane < 2) {
        s_dir4[r0][lane] = aD0;
        s_dir4[r1][lane] = aD1;
    }
    __syncthreads();

    if (tid < RPB * 8) {
        const int r  = tid >> 3;
        const int oo = tid & 7;
        float dir = ((const float*)&s_dir4[r][oo >> 2])[oo & 3];
        const float* zp = s_z[r] + oo * 8;
        float pos = __expf(zp[0]) + 0.25f * __expf(zp[1])
                  + (1.0f / 9.0f) * __expf(zp[2]) + 0.0625f * __expf(zp[3]);
        float neg = __expf(zp[4]) + 0.25f * __expf(zp[5])
                  + (1.0f / 9.0f) * __expf(zp[6]) + 0.0625f * __expf(zp[7]);
        out[(rowbase + r) * ODIM + slice * 8 + oo] = dir + pos - neg;
    }
}

extern "C" void kernel_launch(void* const* d_in, const int* in_sizes, int n_in,
                              void* d_out, int out_size, void* d_ws, size_t ws_size,
                              hipStream_t stream) {
    const float* x    = (const float*)d_in[0];
    const float* dtab = (const float*)d_in[1];
    const float* itab = (const float*)d_in[2];
    float* out = (float*)d_out;

    if (ws_size >= WS_NEEDED) {
        _Float16* wsI = (_Float16*)d_ws;
        _Float16* wsD = wsI + WSI_ELEMS;
        hipLaunchKernelGGL(repack_kernel, dim3(SLICES * (ROWS / 128)), dim3(256), 0, stream,
                           dtab, itab, wsI, wsD);
        hipLaunchKernelGGL(abel_f16_kernel, dim3(BATCH / RPB * SLICES), dim3(TPB), 0, stream,
                           x, wsI, wsD, out);
    } else {
        hipLaunchKernelGGL(abel_fp32_kernel, dim3(BATCH / RPB * SLICES), dim3(256), 0, stream,
                           x, dtab, itab, out);
    }
}

// Round 14
// 55.083 us; speedup vs baseline: 1.0624x; 1.0624x over previous
//
#include <hip/hip_runtime.h>

// ABELSpline: B=1024, D=128, DENSITY=259, ODIM=64, IDIM=512
// out[b,o] = direct[b,o] + sum_n c_n*(exp(z[b,8o+n]) - exp(z[b,8o+4+n])), c_n=(n+1)^-2
// direct[b,o] = sum_{d,k} w[b,d,k] * dtab[d*259 + p[b,d] + k, o]
// z[b,j]      = sum_{d,k} w[b,d,k] * itab[d*259 + p[b,d] + k, j]
// p = floor(256*x); p+3 <= 258 so the reference's mod never wraps.
//
// Round 13: main = EXACT R11 (best total 55.1us: fp16 slice-major tables, wide
// 16B/lane gathers). R12's slice-local repack regressed (stripe+source stream
// 14MB through 4MB L2 -> dirty data evicted anyway; strided reads slower).
// This round: WAVE-PER-ROW repack, 4x fewer requests, fully coalesced:
//  - indirect: wave reads one 2KB row (32B/lane), lane converts its col-oct,
//    writes one h8 (16B); 8 lanes of a slice = one full 128B line per row.
//  - direct: wave = 8 rows (32B/lane read), lane writes its slice's 16B row.
// Same logic that won R11 on main (request-count binder), applied to repack.

constexpr int BATCH = 1024;
constexpr int DIN = 128;
constexpr int DENSITY = 259;
constexpr int ODIM = 64;
constexpr int IDIM = 512;
constexpr int SLICES = 8;           // = #XCDs; 8 outputs / 64 indirect cols each
constexpr int RPB = 8;              // batch rows per block
constexpr int TPB = 512;            // 8 waves; wave wv: rows 2*(wv&3),+1; dims (wv>>2)*64..+63
constexpr int ROWS = DIN * DENSITY; // 33152 table rows = 259 * 128
constexpr size_t WSI_ELEMS = (size_t)SLICES * ROWS * 64;  // fp16 indirect repack
constexpr size_t WSD_ELEMS = (size_t)SLICES * ROWS * 8;   // fp16 direct repack
constexpr size_t WS_NEEDED = (WSI_ELEMS + WSD_ELEMS) * 2; // 38,191,104 B

constexpr int IBLK = ROWS / 4;      // 8288 indirect repack blocks (4 rows each)
constexpr int DBLK = ROWS / 32;     // 1036 direct repack blocks (32 rows each)

typedef _Float16 h8 __attribute__((ext_vector_type(8)));
typedef _Float16 h4 __attribute__((ext_vector_type(4)));

__device__ __forceinline__ void fma4(float4& a, float s, const float4 v) {
    a.x = fmaf(s, v.x, a.x);
    a.y = fmaf(s, v.y, a.y);
    a.z = fmaf(s, v.z, a.z);
    a.w = fmaf(s, v.w, a.w);
}

__device__ __forceinline__ void fma8h(float4& lo, float4& hi, float s, const h8 v) {
    lo.x = fmaf(s, (float)v[0], lo.x);   // -> v_fma_mix_f32
    lo.y = fmaf(s, (float)v[1], lo.y);
    lo.z = fmaf(s, (float)v[2], lo.z);
    lo.w = fmaf(s, (float)v[3], lo.w);
    hi.x = fmaf(s, (float)v[4], hi.x);
    hi.y = fmaf(s, (float)v[5], hi.y);
    hi.z = fmaf(s, (float)v[6], hi.z);
    hi.w = fmaf(s, (float)v[7], hi.w);
}

__device__ __forceinline__ void add4(float4& a, const float4 t) {
    a.x += t.x; a.y += t.y; a.z += t.z; a.w += t.w;
}

__device__ __forceinline__ float4 shfl_xor4(float4 v, int m) {
    return make_float4(__shfl_xor(v.x, m), __shfl_xor(v.y, m),
                       __shfl_xor(v.z, m), __shfl_xor(v.w, m));
}

__device__ __forceinline__ h8 cvt8(const float4 v0, const float4 v1) {
    h8 o = { (_Float16)v0.x, (_Float16)v0.y, (_Float16)v0.z, (_Float16)v0.w,
             (_Float16)v1.x, (_Float16)v1.y, (_Float16)v1.z, (_Float16)v1.w };
    return o;
}

// ---- repack: wave-per-row, fully coalesced, 32B/lane reads + 16B/lane writes.
// blocks [0, IBLK): indirect, 4 rows/block (1 row per wave).
// blocks [IBLK, IBLK+DBLK): direct, 32 rows/block (8 rows per wave).
__global__ __launch_bounds__(256) void repack_kernel(
    const float* __restrict__ dtab,
    const float* __restrict__ itab,
    _Float16* __restrict__ wsI,
    _Float16* __restrict__ wsD)
{
    const int bid  = blockIdx.x;
    const int t    = threadIdx.x;
    const int wv   = t >> 6;
    const int lane = t & 63;
    if (bid < IBLK) {
        const int row = bid * 4 + wv;
        // wave reads the full 2KB row: lane covers cols lane*8..lane*8+7
        const float4* src = (const float4*)(itab + (size_t)row * IDIM) + lane * 2;
        const float4 v0 = src[0];
        const float4 v1 = src[1];
        const int slice = lane >> 3;       // col-oct ownership
        const int c8    = lane & 7;
        *((h8*)wsI + ((size_t)slice * ROWS + row) * 8 + c8) = cvt8(v0, v1);
    } else {
        const int row = (bid - IBLK) * 32 + wv * 8 + (lane >> 3);
        const int sub = lane & 7;          // = slice (8 cols each)
        const float4* src = (const float4*)(dtab + (size_t)row * ODIM) + sub * 2;
        const float4 v0 = src[0];
        const float4 v1 = src[1];
        *((h8*)wsD + (size_t)sub * ROWS + row) = cvt8(v0, v1);
    }
}

// ---- main kernel: EXACT R11 (fp16 slice-major tables, wide 16B/lane gathers)
__global__ __launch_bounds__(TPB) void abel_f16_kernel(
    const float* __restrict__ x,
    const _Float16* __restrict__ wsI,
    const _Float16* __restrict__ wsD,
    float* __restrict__ out)
{
    __shared__ float4 s_w[RPB][DIN];        // spline weights per (row, dim)
    __shared__ int    s_base[RPB][DIN];     // d*259 + floor(256*x)
    __shared__ float  s_zp[2][RPB][64];     // per-half indirect partials
    __shared__ float  s_dp[2][RPB][8];      // per-half direct partials (8 cols)

    const int bid   = blockIdx.x;
    const int slice = bid & (SLICES - 1);   // round-robin -> XCD-pinned stripe
    const int chunk = bid >> 3;             // 0..127
    const int tid   = threadIdx.x;
    const int wv    = tid >> 6;             // 0..7
    const int half  = wv >> 2;              // dim half: 0 or 1
    const int wp    = wv & 3;               // row-pair index
    const int lane  = tid & 63;
    const int rowbase = chunk * RPB;
    const int r0 = 2 * wp, r1 = 2 * wp + 1;
    const int dBeg = half * 64;

    // ---- phase 1: weights + base row index for all (r,d) pairs (2 iters)
    for (int i = tid; i < RPB * DIN; i += TPB) {
        const int r = i >> 7;       // 0..7
        const int d = i & 127;
        float xv = x[(rowbase + r) * DIN + d];
        float t  = xv * 256.0f;     // scale = DENSITY-3 = 256
        float fl = floorf(t);
        float f  = t - fl;
        float f2 = f * f;
        float f3 = f2 * f;
        float om = 1.0f - f;
        float w0 = om * om * om * (1.0f / 6.0f);
        float w1 = (3.0f * f3 - 6.0f * f2 + 4.0f) * (1.0f / 6.0f);
        float w2 = (-3.0f * f3 + 3.0f * f2 + 3.0f * f + 1.0f) * (1.0f / 6.0f);
        float w3 = f3 * (1.0f / 6.0f);
        s_w[r][d]    = make_float4(w0, w1, w2, w3);
        s_base[r][d] = d * DENSITY + (int)fl;
    }
    __syncthreads();

    // ---- phase 2a: indirect stripe, 16B/lane gathers, 2 dims per wave-load.
    // lane = hI (bit5: dim parity) | qI (bits 3-4: knot) | c8 (bits 0-2: col-oct)
    // byte voffset = (base<<7) + (qI<<7) + (c8<<4); one load covers dims d,d+1.
    const int c8 = lane & 7;
    const int qI = (lane >> 3) & 3;
    const int hI = lane >> 5;
    const char* __restrict__ itRaw = (const char*)wsI + (size_t)slice * ROWS * 128;
    const int laneOffI = (qI << 7) + (c8 << 4);

    float4 a0lo = make_float4(0.f, 0.f, 0.f, 0.f);
    float4 a0hi = make_float4(0.f, 0.f, 0.f, 0.f);
    float4 a1lo = make_float4(0.f, 0.f, 0.f, 0.f);
    float4 a1hi = make_float4(0.f, 0.f, 0.f, 0.f);

    #pragma unroll 4
    for (int d = dBeg; d < dBeg + 64; d += 2) {
        const int   dA = d + hI;
        const int   b0 = s_base[r0][dA];
        const int   b1 = s_base[r1][dA];
        const float w0 = ((const float*)&s_w[r0][dA])[qI];
        const float w1 = ((const float*)&s_w[r1][dA])[qI];
        const h8 u0 = *(const h8*)(itRaw + ((b0 << 7) + laneOffI));
        const h8 u1 = *(const h8*)(itRaw + ((b1 << 7) + laneOffI));
        fma8h(a0lo, a0hi, w0, u0);
        fma8h(a1lo, a1hi, w1, u1);
    }
    // reduce over qI (bits 3-4) and hI (bit 5)
    add4(a0lo, shfl_xor4(a0lo, 8));  add4(a0hi, shfl_xor4(a0hi, 8));
    add4(a0lo, shfl_xor4(a0lo, 16)); add4(a0hi, shfl_xor4(a0hi, 16));
    add4(a0lo, shfl_xor4(a0lo, 32)); add4(a0hi, shfl_xor4(a0hi, 32));
    add4(a1lo, shfl_xor4(a1lo, 8));  add4(a1hi, shfl_xor4(a1hi, 8));
    add4(a1lo, shfl_xor4(a1lo, 16)); add4(a1hi, shfl_xor4(a1hi, 16));
    add4(a1lo, shfl_xor4(a1lo, 32)); add4(a1hi, shfl_xor4(a1hi, 32));
    if (lane < 8) {   // lane == c8: owns cols c8*8..c8*8+7
        reinterpret_cast<float4*>(s_zp[half][r0])[c8 * 2]     = a0lo;
        reinterpret_cast<float4*>(s_zp[half][r0])[c8 * 2 + 1] = a0hi;
        reinterpret_cast<float4*>(s_zp[half][r1])[c8 * 2]     = a1lo;
        reinterpret_cast<float4*>(s_zp[half][r1])[c8 * 2 + 1] = a1hi;
    }

    // ---- phase 2b: direct stripe (8 cols), 16B/lane = 8 cols of one knot-row;
    // lane = dd16 (bits 2-5: 16 dims per load) | qD (bits 0-1: knot).
    // byte voffset = (base<<4) + (qD<<4).
    const int qD   = lane & 3;
    const int dd16 = lane >> 2;
    const char* __restrict__ dtRaw = (const char*)wsD + (size_t)slice * ROWS * 16;
    const int laneOffD = qD << 4;

    float4 aD0lo = make_float4(0.f, 0.f, 0.f, 0.f);
    float4 aD0hi = make_float4(0.f, 0.f, 0.f, 0.f);
    float4 aD1lo = make_float4(0.f, 0.f, 0.f, 0.f);
    float4 aD1hi = make_float4(0.f, 0.f, 0.f, 0.f);

    #pragma unroll
    for (int d0 = dBeg; d0 < dBeg + 64; d0 += 16) {
        const int   dA  = d0 + dd16;
        const int   bD0 = s_base[r0][dA];
        const int   bD1 = s_base[r1][dA];
        const float wD0 = ((const float*)&s_w[r0][dA])[qD];
        const float wD1 = ((const float*)&s_w[r1][dA])[qD];
        const h8 g0 = *(const h8*)(dtRaw + ((bD0 << 4) + laneOffD));
        const h8 g1 = *(const h8*)(dtRaw + ((bD1 << 4) + laneOffD));
        fma8h(aD0lo, aD0hi, wD0, g0);
        fma8h(aD1lo, aD1hi, wD1, g1);
    }
    // full-wave reduce (all lanes hold partials of the same 8 direct cols)
    #pragma unroll
    for (int m = 1; m <= 32; m <<= 1) {
        add4(aD0lo, shfl_xor4(aD0lo, m)); add4(aD0hi, shfl_xor4(aD0hi, m));
        add4(aD1lo, shfl_xor4(aD1lo, m)); add4(aD1hi, shfl_xor4(aD1hi, m));
    }
    if (lane == 0) {
        reinterpret_cast<float4*>(s_dp[half][r0])[0] = aD0lo;
        reinterpret_cast<float4*>(s_dp[half][r0])[1] = aD0hi;
        reinterpret_cast<float4*>(s_dp[half][r1])[0] = aD1lo;
        reinterpret_cast<float4*>(s_dp[half][r1])[1] = aD1hi;
    }
    __syncthreads();

    // ---- phase 3: epilogue, 64 threads = 8 rows x 8 outputs; sum the two halves
    if (tid < RPB * 8) {
        const int r  = tid >> 3;
        const int oo = tid & 7;
        float dir = s_dp[0][r][oo] + s_dp[1][r][oo];
        const float* z0 = s_zp[0][r] + oo * 8;
        const float* z1 = s_zp[1][r] + oo * 8;
        float pos = __expf(z0[0] + z1[0]) + 0.25f * __expf(z0[1] + z1[1])
                  + (1.0f / 9.0f) * __expf(z0[2] + z1[2]) + 0.0625f * __expf(z0[3] + z1[3]);
        float neg = __expf(z0[4] + z1[4]) + 0.25f * __expf(z0[5] + z1[5])
                  + (1.0f / 9.0f) * __expf(z0[6] + z1[6]) + 0.0625f * __expf(z0[7] + z1[7]);
        out[(rowbase + r) * ODIM + slice * 8 + oo] = dir + pos - neg;
    }
}

// ---- fp32 fallback (round-7 kernel) for ws_size < WS_NEEDED
__global__ __launch_bounds__(256) void abel_fp32_kernel(
    const float* __restrict__ x,
    const float* __restrict__ dtab,
    const float* __restrict__ itab,
    float* __restrict__ out)
{
    __shared__ float4 s_w[RPB][DIN];
    __shared__ int    s_base[RPB][DIN];
    __shared__ float  s_z[RPB][64];
    __shared__ float4 s_dir4[RPB][2];

    const int bid   = blockIdx.x;
    const int slice = bid & (SLICES - 1);
    const int chunk = bid >> 3;
    const int tid   = threadIdx.x;
    const int wv    = tid >> 6;
    const int lane  = tid & 63;
    const int rowbase = chunk * RPB;

    for (int i = tid; i < RPB * DIN; i += 256) {
        const int r = i >> 7;
        const int d = i & 127;
        float xv = x[(rowbase + r) * DIN + d];
        float t  = xv * 256.0f;
        float fl = floorf(t);
        float f  = t - fl;
        float f2 = f * f;
        float f3 = f2 * f;
        float om = 1.0f - f;
        float w0 = om * om * om * (1.0f / 6.0f);
        float w1 = (3.0f * f3 - 6.0f * f2 + 4.0f) * (1.0f / 6.0f);
        float w2 = (-3.0f * f3 + 3.0f * f2 + 3.0f * f + 1.0f) * (1.0f / 6.0f);
        float w3 = f3 * (1.0f / 6.0f);
        s_w[r][d]    = make_float4(w0, w1, w2, w3);
        s_base[r][d] = d * DENSITY + (int)fl;
    }
    __syncthreads();

    const int q  = lane >> 4;
    const int c4 = lane & 15;
    const float* __restrict__ itL = itab + (size_t)q * IDIM + slice * 64 + c4 * 4;
    const int r0 = 2 * wv, r1 = 2 * wv + 1;

    float4 a0 = make_float4(0.f, 0.f, 0.f, 0.f);
    float4 a1 = make_float4(0.f, 0.f, 0.f, 0.f);
    #pragma unroll 2
    for (int d = 0; d < DIN; ++d) {
        const int   b0 = s_base[r0][d];
        const int   b1 = s_base[r1][d];
        const float w0 = ((const float*)&s_w[r0][d])[q];
        const float w1 = ((const float*)&s_w[r1][d])[q];
        float4 v0 = *(const float4*)(itL + (size_t)b0 * IDIM);
        float4 v1 = *(const float4*)(itL + (size_t)b1 * IDIM);
        fma4(a0, w0, v0);
        fma4(a1, w1, v1);
    }
    add4(a0, shfl_xor4(a0, 16));
    add4(a0, shfl_xor4(a0, 32));
    add4(a1, shfl_xor4(a1, 16));
    add4(a1, shfl_xor4(a1, 32));
    if (q == 0) {
        reinterpret_cast<float4*>(s_z[r0])[c4] = a0;
        reinterpret_cast<float4*>(s_z[r1])[c4] = a1;
    }

    const int dd = lane >> 3;
    const int qD = (lane >> 1) & 3;
    const int jD = lane & 1;
    const float* __restrict__ dtL = dtab + (size_t)qD * ODIM + slice * 8 + jD * 4;

    float4 aD0 = make_float4(0.f, 0.f, 0.f, 0.f);
    float4 aD1 = make_float4(0.f, 0.f, 0.f, 0.f);
    #pragma unroll 2
    for (int d0 = 0; d0 < DIN; d0 += 8) {
        const int   dA  = d0 + dd;
        const int   bD0 = s_base[r0][dA];
        const int   bD1 = s_base[r1][dA];
        const float wD0 = ((const float*)&s_w[r0][dA])[qD];
        const float wD1 = ((const float*)&s_w[r1][dA])[qD];
        float4 u0 = *(const float4*)(dtL + (size_t)bD0 * ODIM);
        float4 u1 = *(const float4*)(dtL + (size_t)bD1 * ODIM);
        fma4(aD0, wD0, u0);
        fma4(aD1, wD1, u1);
    }
    add4(aD0, shfl_xor4(aD0, 2));
    add4(aD0, shfl_xor4(aD0, 4));
    add4(aD0, shfl_xor4(aD0, 8));
    add4(aD0, shfl_xor4(aD0, 16));
    add4(aD0, shfl_xor4(aD0, 32));
    add4(aD1, shfl_xor4(aD1, 2));
    add4(aD1, shfl_xor4(aD1, 4));
    add4(aD1, shfl_xor4(aD1, 8));
    add4(aD1, shfl_xor4(aD1, 16));
    add4(aD1, shfl_xor4(aD1, 32));
    if (lane < 2) {
        s_dir4[r0][lane] = aD0;
        s_dir4[r1][lane] = aD1;
    }
    __syncthreads();

    if (tid < RPB * 8) {
        const int r  = tid >> 3;
        const int oo = tid & 7;
        float dir = ((const float*)&s_dir4[r][oo >> 2])[oo & 3];
        const float* zp = s_z[r] + oo * 8;
        float pos = __expf(zp[0]) + 0.25f * __expf(zp[1])
                  + (1.0f / 9.0f) * __expf(zp[2]) + 0.0625f * __expf(zp[3]);
        float neg = __expf(zp[4]) + 0.25f * __expf(zp[5])
                  + (1.0f / 9.0f) * __expf(zp[6]) + 0.0625f * __expf(zp[7]);
        out[(rowbase + r) * ODIM + slice * 8 + oo] = dir + pos - neg;
    }
}

extern "C" void kernel_launch(void* const* d_in, const int* in_sizes, int n_in,
                              void* d_out, int out_size, void* d_ws, size_t ws_size,
                              hipStream_t stream) {
    const float* x    = (const float*)d_in[0];
    const float* dtab = (const float*)d_in[1];
    const float* itab = (const float*)d_in[2];
    float* out = (float*)d_out;

    if (ws_size >= WS_NEEDED) {
        _Float16* wsI = (_Float16*)d_ws;
        _Float16* wsD = wsI + WSI_ELEMS;
        hipLaunchKernelGGL(repack_kernel, dim3(IBLK + DBLK), dim3(256), 0, stream,
                           dtab, itab, wsI, wsD);
        hipLaunchKernelGGL(abel_f16_kernel, dim3(BATCH / RPB * SLICES), dim3(TPB), 0, stream,
                           x, wsI, wsD, out);
    } else {
        hipLaunchKernelGGL(abel_fp32_kernel, dim3(BATCH / RPB * SLICES), dim3(256), 0, stream,
                           x, dtab, itab, out);
    }
}

// Round 15
// 53.757 us; speedup vs baseline: 1.0887x; 1.0247x over previous
//
#include <hip/hip_runtime.h>

// ABELSpline: B=1024, D=128, DENSITY=259, ODIM=64, IDIM=512
// out[b,o] = direct[b,o] + sum_n c_n*(exp(z[b,8o+n]) - exp(z[b,8o+4+n])), c_n=(n+1)^-2
// direct[b,o] = sum_{d,k} w[b,d,k] * dtab[d*259 + p[b,d] + k, o]
// z[b,j]      = sum_{d,k} w[b,d,k] * itab[d*259 + p[b,d] + k, j]
// p = floor(256*x); p+3 <= 258 so the reference's mod never wraps.
//
// Round 14: R14 (= R11 main + wave-per-row repack, 55.1us) with the main
// kernel's gather loops EXPLICITLY SOFTWARE-PIPELINED (2-stage prefetch +
// unroll 4). VGPR=36 showed the compiler kept only ~1-2 gathers in flight
// per wave (serialized load->use chain at full L2/L3 latency, the R5 failure
// signature). Explicit rotation + counted vmcnt waits -> 3-5 loads in flight.
// Repack and all else byte-identical to R14 (single-variable change).

constexpr int BATCH = 1024;
constexpr int DIN = 128;
constexpr int DENSITY = 259;
constexpr int ODIM = 64;
constexpr int IDIM = 512;
constexpr int SLICES = 8;           // = #XCDs; 8 outputs / 64 indirect cols each
constexpr int RPB = 8;              // batch rows per block
constexpr int TPB = 512;            // 8 waves; wave wv: rows 2*(wv&3),+1; dims (wv>>2)*64..+63
constexpr int ROWS = DIN * DENSITY; // 33152 table rows = 259 * 128
constexpr size_t WSI_ELEMS = (size_t)SLICES * ROWS * 64;  // fp16 indirect repack
constexpr size_t WSD_ELEMS = (size_t)SLICES * ROWS * 8;   // fp16 direct repack
constexpr size_t WS_NEEDED = (WSI_ELEMS + WSD_ELEMS) * 2; // 38,191,104 B

constexpr int IBLK = ROWS / 4;      // 8288 indirect repack blocks (4 rows each)
constexpr int DBLK = ROWS / 32;     // 1036 direct repack blocks (32 rows each)

typedef _Float16 h8 __attribute__((ext_vector_type(8)));
typedef _Float16 h4 __attribute__((ext_vector_type(4)));

__device__ __forceinline__ void fma4(float4& a, float s, const float4 v) {
    a.x = fmaf(s, v.x, a.x);
    a.y = fmaf(s, v.y, a.y);
    a.z = fmaf(s, v.z, a.z);
    a.w = fmaf(s, v.w, a.w);
}

__device__ __forceinline__ void fma8h(float4& lo, float4& hi, float s, const h8 v) {
    lo.x = fmaf(s, (float)v[0], lo.x);   // -> v_fma_mix_f32
    lo.y = fmaf(s, (float)v[1], lo.y);
    lo.z = fmaf(s, (float)v[2], lo.z);
    lo.w = fmaf(s, (float)v[3], lo.w);
    hi.x = fmaf(s, (float)v[4], hi.x);
    hi.y = fmaf(s, (float)v[5], hi.y);
    hi.z = fmaf(s, (float)v[6], hi.z);
    hi.w = fmaf(s, (float)v[7], hi.w);
}

__device__ __forceinline__ void add4(float4& a, const float4 t) {
    a.x += t.x; a.y += t.y; a.z += t.z; a.w += t.w;
}

__device__ __forceinline__ float4 shfl_xor4(float4 v, int m) {
    return make_float4(__shfl_xor(v.x, m), __shfl_xor(v.y, m),
                       __shfl_xor(v.z, m), __shfl_xor(v.w, m));
}

__device__ __forceinline__ h8 cvt8(const float4 v0, const float4 v1) {
    h8 o = { (_Float16)v0.x, (_Float16)v0.y, (_Float16)v0.z, (_Float16)v0.w,
             (_Float16)v1.x, (_Float16)v1.y, (_Float16)v1.z, (_Float16)v1.w };
    return o;
}

// ---- repack: wave-per-row, fully coalesced (R14, unchanged).
__global__ __launch_bounds__(256) void repack_kernel(
    const float* __restrict__ dtab,
    const float* __restrict__ itab,
    _Float16* __restrict__ wsI,
    _Float16* __restrict__ wsD)
{
    const int bid  = blockIdx.x;
    const int t    = threadIdx.x;
    const int wv   = t >> 6;
    const int lane = t & 63;
    if (bid < IBLK) {
        const int row = bid * 4 + wv;
        const float4* src = (const float4*)(itab + (size_t)row * IDIM) + lane * 2;
        const float4 v0 = src[0];
        const float4 v1 = src[1];
        const int slice = lane >> 3;
        const int c8    = lane & 7;
        *((h8*)wsI + ((size_t)slice * ROWS + row) * 8 + c8) = cvt8(v0, v1);
    } else {
        const int row = (bid - IBLK) * 32 + wv * 8 + (lane >> 3);
        const int sub = lane & 7;
        const float4* src = (const float4*)(dtab + (size_t)row * ODIM) + sub * 2;
        const float4 v0 = src[0];
        const float4 v1 = src[1];
        *((h8*)wsD + (size_t)sub * ROWS + row) = cvt8(v0, v1);
    }
}

// ---- main kernel: R11 structure + explicit 2-stage pipelined gather loops
__global__ __launch_bounds__(TPB) void abel_f16_kernel(
    const float* __restrict__ x,
    const _Float16* __restrict__ wsI,
    const _Float16* __restrict__ wsD,
    float* __restrict__ out)
{
    __shared__ float4 s_w[RPB][DIN];        // spline weights per (row, dim)
    __shared__ int    s_base[RPB][DIN];     // d*259 + floor(256*x)
    __shared__ float  s_zp[2][RPB][64];     // per-half indirect partials
    __shared__ float  s_dp[2][RPB][8];      // per-half direct partials (8 cols)

    const int bid   = blockIdx.x;
    const int slice = bid & (SLICES - 1);   // round-robin -> XCD-pinned stripe
    const int chunk = bid >> 3;             // 0..127
    const int tid   = threadIdx.x;
    const int wv    = tid >> 6;             // 0..7
    const int half  = wv >> 2;              // dim half: 0 or 1
    const int wp    = wv & 3;               // row-pair index
    const int lane  = tid & 63;
    const int rowbase = chunk * RPB;
    const int r0 = 2 * wp, r1 = 2 * wp + 1;
    const int dBeg = half * 64;

    // ---- phase 1: weights + base row index for all (r,d) pairs (2 iters)
    for (int i = tid; i < RPB * DIN; i += TPB) {
        const int r = i >> 7;       // 0..7
        const int d = i & 127;
        float xv = x[(rowbase + r) * DIN + d];
        float t  = xv * 256.0f;     // scale = DENSITY-3 = 256
        float fl = floorf(t);
        float f  = t - fl;
        float f2 = f * f;
        float f3 = f2 * f;
        float om = 1.0f - f;
        float w0 = om * om * om * (1.0f / 6.0f);
        float w1 = (3.0f * f3 - 6.0f * f2 + 4.0f) * (1.0f / 6.0f);
        float w2 = (-3.0f * f3 + 3.0f * f2 + 3.0f * f + 1.0f) * (1.0f / 6.0f);
        float w3 = f3 * (1.0f / 6.0f);
        s_w[r][d]    = make_float4(w0, w1, w2, w3);
        s_base[r][d] = d * DENSITY + (int)fl;
    }
    __syncthreads();

    // ---- phase 2a: indirect stripe, 16B/lane gathers, 2 dims per wave-load.
    // lane = hI (bit5: dim parity) | qI (bits 3-4: knot) | c8 (bits 0-2: col-oct)
    // byte voffset = (base<<7) + (qI<<7) + (c8<<4); one load covers dims d,d+1.
    // Explicit 2-stage pipeline: prefetch iter i+1's loads before consuming i.
    const int c8 = lane & 7;
    const int qI = (lane >> 3) & 3;
    const int hI = lane >> 5;
    const char* __restrict__ itRaw = (const char*)wsI + (size_t)slice * ROWS * 128;
    const int laneOffI = (qI << 7) + (c8 << 4);

    float4 a0lo = make_float4(0.f, 0.f, 0.f, 0.f);
    float4 a0hi = make_float4(0.f, 0.f, 0.f, 0.f);
    float4 a1lo = make_float4(0.f, 0.f, 0.f, 0.f);
    float4 a1hi = make_float4(0.f, 0.f, 0.f, 0.f);

    h8 u0 = *(const h8*)(itRaw + ((s_base[r0][dBeg + hI] << 7) + laneOffI));
    h8 u1 = *(const h8*)(itRaw + ((s_base[r1][dBeg + hI] << 7) + laneOffI));
    #pragma unroll 4
    for (int d = dBeg; d < dBeg + 62; d += 2) {
        const int dN = d + 2 + hI;
        h8 n0 = *(const h8*)(itRaw + ((s_base[r0][dN] << 7) + laneOffI));
        h8 n1 = *(const h8*)(itRaw + ((s_base[r1][dN] << 7) + laneOffI));
        const float w0 = ((const float*)&s_w[r0][d + hI])[qI];
        const float w1 = ((const float*)&s_w[r1][d + hI])[qI];
        fma8h(a0lo, a0hi, w0, u0);
        fma8h(a1lo, a1hi, w1, u1);
        u0 = n0; u1 = n1;
    }
    {
        const int dL = dBeg + 62 + hI;
        const float w0 = ((const float*)&s_w[r0][dL])[qI];
        const float w1 = ((const float*)&s_w[r1][dL])[qI];
        fma8h(a0lo, a0hi, w0, u0);
        fma8h(a1lo, a1hi, w1, u1);
    }
    // reduce over qI (bits 3-4) and hI (bit 5)
    add4(a0lo, shfl_xor4(a0lo, 8));  add4(a0hi, shfl_xor4(a0hi, 8));
    add4(a0lo, shfl_xor4(a0lo, 16)); add4(a0hi, shfl_xor4(a0hi, 16));
    add4(a0lo, shfl_xor4(a0lo, 32)); add4(a0hi, shfl_xor4(a0hi, 32));
    add4(a1lo, shfl_xor4(a1lo, 8));  add4(a1hi, shfl_xor4(a1hi, 8));
    add4(a1lo, shfl_xor4(a1lo, 16)); add4(a1hi, shfl_xor4(a1hi, 16));
    add4(a1lo, shfl_xor4(a1lo, 32)); add4(a1hi, shfl_xor4(a1hi, 32));
    if (lane < 8) {   // lane == c8: owns cols c8*8..c8*8+7
        reinterpret_cast<float4*>(s_zp[half][r0])[c8 * 2]     = a0lo;
        reinterpret_cast<float4*>(s_zp[half][r0])[c8 * 2 + 1] = a0hi;
        reinterpret_cast<float4*>(s_zp[half][r1])[c8 * 2]     = a1lo;
        reinterpret_cast<float4*>(s_zp[half][r1])[c8 * 2 + 1] = a1hi;
    }

    // ---- phase 2b: direct stripe (8 cols), 16B/lane = 8 cols of one knot-row;
    // lane = dd16 (bits 2-5: 16 dims per load) | qD (bits 0-1: knot).
    // byte voffset = (base<<4) + (qD<<4). Same 2-stage pipeline.
    const int qD   = lane & 3;
    const int dd16 = lane >> 2;
    const char* __restrict__ dtRaw = (const char*)wsD + (size_t)slice * ROWS * 16;
    const int laneOffD = qD << 4;

    float4 aD0lo = make_float4(0.f, 0.f, 0.f, 0.f);
    float4 aD0hi = make_float4(0.f, 0.f, 0.f, 0.f);
    float4 aD1lo = make_float4(0.f, 0.f, 0.f, 0.f);
    float4 aD1hi = make_float4(0.f, 0.f, 0.f, 0.f);

    h8 g0 = *(const h8*)(dtRaw + ((s_base[r0][dBeg + dd16] << 4) + laneOffD));
    h8 g1 = *(const h8*)(dtRaw + ((s_base[r1][dBeg + dd16] << 4) + laneOffD));
    #pragma unroll
    for (int d0 = dBeg; d0 < dBeg + 48; d0 += 16) {
        const int dN = d0 + 16 + dd16;
        h8 p0 = *(const h8*)(dtRaw + ((s_base[r0][dN] << 4) + laneOffD));
        h8 p1 = *(const h8*)(dtRaw + ((s_base[r1][dN] << 4) + laneOffD));
        const float wD0 = ((const float*)&s_w[r0][d0 + dd16])[qD];
        const float wD1 = ((const float*)&s_w[r1][d0 + dd16])[qD];
        fma8h(aD0lo, aD0hi, wD0, g0);
        fma8h(aD1lo, aD1hi, wD1, g1);
        g0 = p0; g1 = p1;
    }
    {
        const int dL = dBeg + 48 + dd16;
        const float wD0 = ((const float*)&s_w[r0][dL])[qD];
        const float wD1 = ((const float*)&s_w[r1][dL])[qD];
        fma8h(aD0lo, aD0hi, wD0, g0);
        fma8h(aD1lo, aD1hi, wD1, g1);
    }
    // full-wave reduce (all lanes hold partials of the same 8 direct cols)
    #pragma unroll
    for (int m = 1; m <= 32; m <<= 1) {
        add4(aD0lo, shfl_xor4(aD0lo, m)); add4(aD0hi, shfl_xor4(aD0hi, m));
        add4(aD1lo, shfl_xor4(aD1lo, m)); add4(aD1hi, shfl_xor4(aD1hi, m));
    }
    if (lane == 0) {
        reinterpret_cast<float4*>(s_dp[half][r0])[0] = aD0lo;
        reinterpret_cast<float4*>(s_dp[half][r0])[1] = aD0hi;
        reinterpret_cast<float4*>(s_dp[half][r1])[0] = aD1lo;
        reinterpret_cast<float4*>(s_dp[half][r1])[1] = aD1hi;
    }
    __syncthreads();

    // ---- phase 3: epilogue, 64 threads = 8 rows x 8 outputs; sum the two halves
    if (tid < RPB * 8) {
        const int r  = tid >> 3;
        const int oo = tid & 7;
        float dir = s_dp[0][r][oo] + s_dp[1][r][oo];
        const float* z0 = s_zp[0][r] + oo * 8;
        const float* z1 = s_zp[1][r] + oo * 8;
        float pos = __expf(z0[0] + z1[0]) + 0.25f * __expf(z0[1] + z1[1])
                  + (1.0f / 9.0f) * __expf(z0[2] + z1[2]) + 0.0625f * __expf(z0[3] + z1[3]);
        float neg = __expf(z0[4] + z1[4]) + 0.25f * __expf(z0[5] + z1[5])
                  + (1.0f / 9.0f) * __expf(z0[6] + z1[6]) + 0.0625f * __expf(z0[7] + z1[7]);
        out[(rowbase + r) * ODIM + slice * 8 + oo] = dir + pos - neg;
    }
}

// ---- fp32 fallback (round-7 kernel) for ws_size < WS_NEEDED
__global__ __launch_bounds__(256) void abel_fp32_kernel(
    const float* __restrict__ x,
    const float* __restrict__ dtab,
    const float* __restrict__ itab,
    float* __restrict__ out)
{
    __shared__ float4 s_w[RPB][DIN];
    __shared__ int    s_base[RPB][DIN];
    __shared__ float  s_z[RPB][64];
    __shared__ float4 s_dir4[RPB][2];

    const int bid   = blockIdx.x;
    const int slice = bid & (SLICES - 1);
    const int chunk = bid >> 3;
    const int tid   = threadIdx.x;
    const int wv    = tid >> 6;
    const int lane  = tid & 63;
    const int rowbase = chunk * RPB;

    for (int i = tid; i < RPB * DIN; i += 256) {
        const int r = i >> 7;
        const int d = i & 127;
        float xv = x[(rowbase + r) * DIN + d];
        float t  = xv * 256.0f;
        float fl = floorf(t);
        float f  = t - fl;
        float f2 = f * f;
        float f3 = f2 * f;
        float om = 1.0f - f;
        float w0 = om * om * om * (1.0f / 6.0f);
        float w1 = (3.0f * f3 - 6.0f * f2 + 4.0f) * (1.0f / 6.0f);
        float w2 = (-3.0f * f3 + 3.0f * f2 + 3.0f * f + 1.0f) * (1.0f / 6.0f);
        float w3 = f3 * (1.0f / 6.0f);
        s_w[r][d]    = make_float4(w0, w1, w2, w3);
        s_base[r][d] = d * DENSITY + (int)fl;
    }
    __syncthreads();

    const int q  = lane >> 4;
    const int c4 = lane & 15;
    const float* __restrict__ itL = itab + (size_t)q * IDIM + slice * 64 + c4 * 4;
    const int r0 = 2 * wv, r1 = 2 * wv + 1;

    float4 a0 = make_float4(0.f, 0.f, 0.f, 0.f);
    float4 a1 = make_float4(0.f, 0.f, 0.f, 0.f);
    #pragma unroll 2
    for (int d = 0; d < DIN; ++d) {
        const int   b0 = s_base[r0][d];
        const int   b1 = s_base[r1][d];
        const float w0 = ((const float*)&s_w[r0][d])[q];
        const float w1 = ((const float*)&s_w[r1][d])[q];
        float4 v0 = *(const float4*)(itL + (size_t)b0 * IDIM);
        float4 v1 = *(const float4*)(itL + (size_t)b1 * IDIM);
        fma4(a0, w0, v0);
        fma4(a1, w1, v1);
    }
    add4(a0, shfl_xor4(a0, 16));
    add4(a0, shfl_xor4(a0, 32));
    add4(a1, shfl_xor4(a1, 16));
    add4(a1, shfl_xor4(a1, 32));
    if (q == 0) {
        reinterpret_cast<float4*>(s_z[r0])[c4] = a0;
        reinterpret_cast<float4*>(s_z[r1])[c4] = a1;
    }

    const int dd = lane >> 3;
    const int qD = (lane >> 1) & 3;
    const int jD = lane & 1;
    const float* __restrict__ dtL = dtab + (size_t)qD * ODIM + slice * 8 + jD * 4;

    float4 aD0 = make_float4(0.f, 0.f, 0.f, 0.f);
    float4 aD1 = make_float4(0.f, 0.f, 0.f, 0.f);
    #pragma unroll 2
    for (int d0 = 0; d0 < DIN; d0 += 8) {
        const int   dA  = d0 + dd;
        const int   bD0 = s_base[r0][dA];
        const int   bD1 = s_base[r1][dA];
        const float wD0 = ((const float*)&s_w[r0][dA])[qD];
        const float wD1 = ((const float*)&s_w[r1][dA])[qD];
        float4 u0 = *(const float4*)(dtL + (size_t)bD0 * ODIM);
        float4 u1 = *(const float4*)(dtL + (size_t)bD1 * ODIM);
        fma4(aD0, wD0, u0);
        fma4(aD1, wD1, u1);
    }
    add4(aD0, shfl_xor4(aD0, 2));
    add4(aD0, shfl_xor4(aD0, 4));
    add4(aD0, shfl_xor4(aD0, 8));
    add4(aD0, shfl_xor4(aD0, 16));
    add4(aD0, shfl_xor4(aD0, 32));
    add4(aD1, shfl_xor4(aD1, 2));
    add4(aD1, shfl_xor4(aD1, 4));
    add4(aD1, shfl_xor4(aD1, 8));
    add4(aD1, shfl_xor4(aD1, 16));
    add4(aD1, shfl_xor4(aD1, 32));
    if (lane < 2) {
        s_dir4[r0][lane] = aD0;
        s_dir4[r1][lane] = aD1;
    }
    __syncthreads();

    if (tid < RPB * 8) {
        const int r  = tid >> 3;
        const int oo = tid & 7;
        float dir = ((const float*)&s_dir4[r][oo >> 2])[oo & 3];
        const float* zp = s_z[r] + oo * 8;
        float pos = __expf(zp[0]) + 0.25f * __expf(zp[1])
                  + (1.0f / 9.0f) * __expf(zp[2]) + 0.0625f * __expf(zp[3]);
        float neg = __expf(zp[4]) + 0.25f * __expf(zp[5])
                  + (1.0f / 9.0f) * __expf(zp[6]) + 0.0625f * __expf(zp[7]);
        out[(rowbase + r) * ODIM + slice * 8 + oo] = dir + pos - neg;
    }
}

extern "C" void kernel_launch(void* const* d_in, const int* in_sizes, int n_in,
                              void* d_out, int out_size, void* d_ws, size_t ws_size,
                              hipStream_t stream) {
    const float* x    = (const float*)d_in[0];
    const float* dtab = (const float*)d_in[1];
    const float* itab = (const float*)d_in[2];
    float* out = (float*)d_out;

    if (ws_size >= WS_NEEDED) {
        _Float16* wsI = (_Float16*)d_ws;
        _Float16* wsD = wsI + WSI_ELEMS;
        hipLaunchKernelGGL(repack_kernel, dim3(IBLK + DBLK), dim3(256), 0, stream,
                           dtab, itab, wsI, wsD);
        hipLaunchKernelGGL(abel_f16_kernel, dim3(BATCH / RPB * SLICES), dim3(TPB), 0, stream,
                           x, wsI, wsD, out);
    } else {
        hipLaunchKernelGGL(abel_fp32_kernel, dim3(BATCH / RPB * SLICES), dim3(256), 0, stream,
                           x, dtab, itab, out);
    }
}